// Round 7
// baseline (503.194 us; speedup 1.0000x reference)
//
#include <hip/hip_runtime.h>

// Problem constants (match reference setup_inputs)
#define GN 100000
#define GE 1600000
#define GF 128      // F_IN
#define GH 128      // hidden
#define GC 64       // out channels

#define NB 392      // dst buckets of width 256 (392*256 = 100352 >= N)
#define EDGE_BLOCKS ((GE + 2047) / 2048)              // 782 (8 edges/thread)
#define CASTX_BLOCKS 12500                            // GN*GF/4 / 256 exactly

typedef __attribute__((ext_vector_type(8))) short v8s;   // 8 bf16 (4 VGPRs)
typedef __attribute__((ext_vector_type(4))) float v4f;   // 4 fp32
typedef __attribute__((ext_vector_type(2))) float v2f;   // 2 fp32 (pk_add_f32)

__device__ __forceinline__ unsigned short f2bf(float f) {
    union { float f; unsigned u; } a; a.f = f;
    unsigned r = a.u + 0x7fff + ((a.u >> 16) & 1);  // RNE
    return (unsigned short)(r >> 16);
}
__device__ __forceinline__ float bf2f(unsigned short b) {
    union { unsigned u; float f; } a; a.u = ((unsigned)b) << 16;
    return a.f;
}
// word of 2 bf16 -> {lo_as_f32, hi_as_f32}
__device__ __forceinline__ v2f cvt2(unsigned w) {
    union { unsigned u; float f; } lo, hi;
    lo.u = w << 16; hi.u = w & 0xffff0000u;
    return (v2f){lo.f, hi.f};
}

// ---------------------------------------------------------------------------
// PREP: blocks [0,EDGE_BLOCKS) = per-edge degree atomics (no LDS/barriers);
// rest = bf16 casts (x + weights).
__global__ __launch_bounds__(256) void prep_kernel(
    int* __restrict__ deg, const int* __restrict__ dst,
    unsigned short* __restrict__ xb, const float* __restrict__ x,
    unsigned short* w1l, unsigned short* w1r,
    unsigned short* w2l, unsigned short* w2r,
    const float* W1l, const float* W1r,
    const float* W2l, const float* W2r)
{
    int tid = threadIdx.x;
    int blk = blockIdx.x;

    if (blk < EDGE_BLOCKS) {
        int e0 = blk * 2048 + tid;
        #pragma unroll
        for (int j = 0; j < 8; ++j) {
            int e = e0 + j * 256;
            if (e < GE) atomicAdd(&deg[dst[e]], 1);   // fire-and-forget
        }
        return;
    }
    int cb = blk - EDGE_BLOCKS;
    if (cb < CASTX_BLOCKS) {
        int i = cb * 256 + tid;
        float4 v = ((const float4*)x)[i];
        ushort4 u;
        u.x = f2bf(v.x); u.y = f2bf(v.y); u.z = f2bf(v.z); u.w = f2bf(v.w);
        ((ushort4*)xb)[i] = u;
        return;
    }
    int i = (cb - CASTX_BLOCKS) * 256 + tid;
    const float* s; unsigned short* d; int off;
    if      (i <  4096) { s = W1l; d = w1l; off = i; }
    else if (i <  8192) { s = W1r; d = w1r; off = i - 4096; }
    else if (i < 10240) { s = W2l; d = w2l; off = i - 8192; }
    else if (i < 12288) { s = W2r; d = w2r; off = i - 10240; }
    else return;
    float4 v = ((const float4*)s)[off];
    ushort4 u;
    u.x = f2bf(v.x); u.y = f2bf(v.y); u.z = f2bf(v.z); u.w = f2bf(v.w);
    ((ushort4*)d)[off] = u;
}

// SCAN1: per-bucket degree sums (392 blocks x 256 rows).
__global__ __launch_bounds__(256) void scan1_kernel(
    int* __restrict__ bsum, const int* __restrict__ deg)
{
    __shared__ int ws[4];
    int t = threadIdx.x, b = blockIdx.x;
    int d = b * 256 + t;
    int v = (d < GN) ? deg[d] : 0;
    #pragma unroll
    for (int m = 1; m < 64; m <<= 1) v += __shfl_xor(v, m);
    if ((t & 63) == 0) ws[t >> 6] = v;
    __syncthreads();
    if (t == 0) bsum[b] = ws[0] + ws[1] + ws[2] + ws[3];
}

// SCAN2: inline scan of bucket sums -> base; LDS scan of deg -> row_ptr,
// cursor init, invc, dis.
__global__ __launch_bounds__(256) void scan2_kernel(
    int* __restrict__ row_ptr, int* __restrict__ cursor,
    float* __restrict__ invc, float* __restrict__ dis,
    const int* __restrict__ deg, const int* __restrict__ bsum)
{
    __shared__ int ssum[256];
    __shared__ int bstart_s;
    int t = threadIdx.x, b = blockIdx.x;

    int c0 = (2 * t < NB) ? bsum[2 * t] : 0;
    int c1 = (2 * t + 1 < NB) ? bsum[2 * t + 1] : 0;
    int sc = c0 + c1;
    ssum[t] = sc;
    __syncthreads();
    for (int off = 1; off < 256; off <<= 1) {
        int v = (t >= off) ? ssum[t - off] : 0;
        __syncthreads();
        ssum[t] += v;
        __syncthreads();
    }
    int pb = ssum[t] - sc;
    if (2 * t == b)     bstart_s = pb;
    if (2 * t + 1 == b) bstart_s = pb + c0;
    if (b == 0 && t == 0) row_ptr[GN] = GE;
    __syncthreads();
    int base = bstart_s;

    int d = b * 256 + t;
    int dg = (d < GN) ? deg[d] : 0;
    ssum[t] = dg;
    __syncthreads();
    for (int off = 1; off < 256; off <<= 1) {
        int v = (t >= off) ? ssum[t - off] : 0;
        __syncthreads();
        ssum[t] += v;
        __syncthreads();
    }
    int ex = ssum[t] - dg;
    if (d < GN) {
        int rp = base + ex;
        row_ptr[d] = rp;
        cursor[d] = rp;
        float c = (float)dg;
        invc[d] = 1.0f / fmaxf(c, 1.0f);
        dis[d] = rsqrtf(c + 1.0f);
    }
}

// SCATTER: csr[atomicAdd(cursor[dst])] = src. Throughput-bound atomics
// (avg 16 collisions/row) + random 4B writes.
__global__ __launch_bounds__(256) void scatter_kernel(
    int* __restrict__ csr, int* __restrict__ cursor,
    const int* __restrict__ src, const int* __restrict__ dst)
{
    int e0 = blockIdx.x * 2048 + threadIdx.x;
    #pragma unroll
    for (int j = 0; j < 8; ++j) {
        int e = e0 + j * 256;
        if (e < GE) {
            int pos = atomicAdd(&cursor[dst[e]], 1);
            csr[pos] = src[e];
        }
    }
}

// ---------------------------------------------------------------------------
// FUSED GEMM v2: ONE WAVE PER 64-ROW TILE (no barriers, 17.4 KB LDS/block).
__global__ __launch_bounds__(64, 2) void fused_gemm_kernel(
    unsigned short* __restrict__ P, unsigned short* __restrict__ Q,
    const unsigned short* __restrict__ A1, const unsigned short* __restrict__ A2,
    const unsigned short* __restrict__ W1, const unsigned short* __restrict__ W2,
    const unsigned short* __restrict__ Wl, const unsigned short* __restrict__ Wr,
    const float* __restrict__ b1, const float* __restrict__ b2, int M)
{
    __shared__ unsigned short hs[64][136];   // 17.4 KB; row stride 272B -> 2-way alias (free)

    int lane = threadIdx.x;                  // 0..63, one wave
    int lm = lane & 15, quad = lane >> 4;
    int m_base = blockIdx.x * 64;

    // ---- phase 1: layer-1 dual GEMM, full N=128, A loaded once ----
    v4f acc[4][8];
    #pragma unroll
    for (int mt = 0; mt < 4; ++mt)
        #pragma unroll
        for (int nt = 0; nt < 8; ++nt) acc[mt][nt] = (v4f){0.f,0.f,0.f,0.f};

    #pragma unroll
    for (int ks = 0; ks < 4; ++ks) {
        int koff = ks * 32 + quad * 8;
        v8s a1[4], a2[4];
        #pragma unroll
        for (int mt = 0; mt < 4; ++mt) {
            int row = m_base + mt * 16 + lm;
            if (row < M) {
                a1[mt] = *(const v8s*)(A1 + (size_t)row * 128 + koff);
                a2[mt] = *(const v8s*)(A2 + (size_t)row * 128 + koff);
            } else {
                a1[mt] = (v8s){0,0,0,0,0,0,0,0};
                a2[mt] = (v8s){0,0,0,0,0,0,0,0};
            }
        }
        v8s w1[8], w2[8];
        #pragma unroll
        for (int nt = 0; nt < 8; ++nt) {
            int col = nt * 16 + lm;
            w1[nt] = *(const v8s*)(W1 + (size_t)col * 128 + koff);
            w2[nt] = *(const v8s*)(W2 + (size_t)col * 128 + koff);
        }
        #pragma unroll
        for (int mt = 0; mt < 4; ++mt)
            #pragma unroll
            for (int nt = 0; nt < 8; ++nt) {
                acc[mt][nt] = __builtin_amdgcn_mfma_f32_16x16x32_bf16(a1[mt], w1[nt], acc[mt][nt], 0, 0, 0);
                acc[mt][nt] = __builtin_amdgcn_mfma_f32_16x16x32_bf16(a2[mt], w2[nt], acc[mt][nt], 0, 0, 0);
            }
    }

    // epilogue -> LDS (C layout: col = nt*16+lm, row = mt*16 + quad*4 + r)
    #pragma unroll
    for (int mt = 0; mt < 4; ++mt)
        #pragma unroll
        for (int r = 0; r < 4; ++r) {
            int rl = mt * 16 + quad * 4 + r;
            #pragma unroll
            for (int nt = 0; nt < 8; ++nt) {
                int col = nt * 16 + lm;
                float v = acc[mt][nt][r] + b1[col];
                hs[rl][col] = f2bf(fmaxf(v, 0.f));
            }
        }
    // same-wave LDS RAW: compiler inserts lgkmcnt wait; no barrier needed.

    // ---- phase 2: layer-2 dual GEMM, A from LDS ----
    v4f accP[4][4], accQ[4][4];
    #pragma unroll
    for (int mt = 0; mt < 4; ++mt)
        #pragma unroll
        for (int nt = 0; nt < 4; ++nt) {
            accP[mt][nt] = (v4f){0.f,0.f,0.f,0.f};
            accQ[mt][nt] = (v4f){0.f,0.f,0.f,0.f};
        }

    #pragma unroll
    for (int ks = 0; ks < 4; ++ks) {
        int koff = ks * 32 + quad * 8;
        v8s af[4], bl[4], br[4];
        #pragma unroll
        for (int mt = 0; mt < 4; ++mt)
            af[mt] = *(const v8s*)&hs[mt * 16 + lm][koff];
        #pragma unroll
        for (int nt = 0; nt < 4; ++nt) {
            int col = nt * 16 + lm;
            bl[nt] = *(const v8s*)(Wl + (size_t)col * 128 + koff);
            br[nt] = *(const v8s*)(Wr + (size_t)col * 128 + koff);
        }
        #pragma unroll
        for (int mt = 0; mt < 4; ++mt)
            #pragma unroll
            for (int nt = 0; nt < 4; ++nt) {
                accP[mt][nt] = __builtin_amdgcn_mfma_f32_16x16x32_bf16(af[mt], bl[nt], accP[mt][nt], 0, 0, 0);
                accQ[mt][nt] = __builtin_amdgcn_mfma_f32_16x16x32_bf16(af[mt], br[nt], accQ[mt][nt], 0, 0, 0);
            }
    }

    #pragma unroll
    for (int mt = 0; mt < 4; ++mt)
        #pragma unroll
        for (int r = 0; r < 4; ++r) {
            int row = m_base + mt * 16 + quad * 4 + r;
            if (row >= M) continue;
            #pragma unroll
            for (int nt = 0; nt < 4; ++nt) {
                int col = nt * 16 + lm;
                P[(size_t)row * 64 + col] = f2bf(accP[mt][nt][r]);
                Q[(size_t)row * 64 + col] = f2bf(accQ[mt][nt][r] + b2[col]);
            }
        }
}

// ---------------------------------------------------------------------------
// GATHER v3 (mean over 128-col bf16 rows): one wave per dst row; 16 lanes x
// 16B cover a 256B row -> FOUR rows per dwordx4 instruction. Scalar csr idx
// (wave-uniform), cndmask row-select, shfl_xor(16,32) replica reduce.
__global__ __launch_bounds__(256) void gather_mean128_kernel(
    unsigned short* __restrict__ out, const unsigned short* __restrict__ in,
    const float* __restrict__ invc, const int* __restrict__ row_ptr,
    const int* __restrict__ csr, int N)
{
    int wid = (blockIdx.x * 256 + threadIdx.x) >> 6;
    int lane = threadIdx.x & 63;
    if (wid >= N) return;
    int beg = __builtin_amdgcn_readfirstlane(row_ptr[wid]);
    int end = __builtin_amdgcn_readfirstlane(row_ptr[wid + 1]);
    int d = end - beg;
    int grp = lane >> 4, lx = lane & 15;
    v2f a0 = {0.f,0.f}, a1 = {0.f,0.f}, a2 = {0.f,0.f}, a3 = {0.f,0.f};

    int nf = d >> 2;
    #pragma unroll 4
    for (int t = 0; t < nf; ++t) {
        int j = beg + t * 4;
        int s0 = csr[j], s1 = csr[j + 1], s2 = csr[j + 2], s3 = csr[j + 3];
        int sa = (lane & 16) ? s1 : s0;
        int sb = (lane & 16) ? s3 : s2;
        int ss = (lane & 32) ? sb : sa;
        uint4 v = ((const uint4*)(in + (size_t)ss * 128))[lx];
        a0 += cvt2(v.x); a1 += cvt2(v.y); a2 += cvt2(v.z); a3 += cvt2(v.w);
    }
    int rem = d & 3;
    if (rem) {
        int j = beg + nf * 4;
        int c1 = (rem > 1) ? 1 : 0;
        int c2 = (rem > 2) ? 2 : c1;
        int s0 = csr[j], s1 = csr[j + c1], s2 = csr[j + c2], s3 = s2;
        int sa = (lane & 16) ? s1 : s0;
        int sb = (lane & 16) ? s3 : s2;
        int ss = (lane & 32) ? sb : sa;
        uint4 v = ((const uint4*)(in + (size_t)ss * 128))[lx];
        bool ok = grp < rem;
        v.x = ok ? v.x : 0u; v.y = ok ? v.y : 0u;
        v.z = ok ? v.z : 0u; v.w = ok ? v.w : 0u;
        a0 += cvt2(v.x); a1 += cvt2(v.y); a2 += cvt2(v.z); a3 += cvt2(v.w);
    }
    // reduce the 4 replicas (lane bits 4,5)
    a0.x += __shfl_xor(a0.x, 16); a0.y += __shfl_xor(a0.y, 16);
    a1.x += __shfl_xor(a1.x, 16); a1.y += __shfl_xor(a1.y, 16);
    a2.x += __shfl_xor(a2.x, 16); a2.y += __shfl_xor(a2.y, 16);
    a3.x += __shfl_xor(a3.x, 16); a3.y += __shfl_xor(a3.y, 16);
    a0.x += __shfl_xor(a0.x, 32); a0.y += __shfl_xor(a0.y, 32);
    a1.x += __shfl_xor(a1.x, 32); a1.y += __shfl_xor(a1.y, 32);
    a2.x += __shfl_xor(a2.x, 32); a2.y += __shfl_xor(a2.y, 32);
    a3.x += __shfl_xor(a3.x, 32); a3.y += __shfl_xor(a3.y, 32);
    if (grp == 0) {
        float ic = invc[wid];
        uint4 o;
        o.x = (unsigned)f2bf(a0.x * ic) | ((unsigned)f2bf(a0.y * ic) << 16);
        o.y = (unsigned)f2bf(a1.x * ic) | ((unsigned)f2bf(a1.y * ic) << 16);
        o.z = (unsigned)f2bf(a2.x * ic) | ((unsigned)f2bf(a2.y * ic) << 16);
        o.w = (unsigned)f2bf(a3.x * ic) | ((unsigned)f2bf(a3.y * ic) << 16);
        ((uint4*)(out + (size_t)wid * 128))[lx] = o;
    }
}

// GATHER v3 over p (64-col bf16 rows = 128B): 8 lanes x 16B per row ->
// EIGHT rows per dwordx4 instruction. Same scalar-idx + cndmask-select +
// shfl_xor(8,16,32) reduction. Epilogue folds q, invc, dis.
__global__ __launch_bounds__(256) void gather_combine_kernel(
    unsigned short* __restrict__ h2s, const unsigned short* __restrict__ p,
    const unsigned short* __restrict__ q,
    const float* __restrict__ invc, const float* __restrict__ dis,
    const int* __restrict__ row_ptr, const int* __restrict__ csr, int N)
{
    int wid = (blockIdx.x * 256 + threadIdx.x) >> 6;
    int lane = threadIdx.x & 63;
    if (wid >= N) return;
    int beg = __builtin_amdgcn_readfirstlane(row_ptr[wid]);
    int end = __builtin_amdgcn_readfirstlane(row_ptr[wid + 1]);
    int d = end - beg;
    int grp = lane >> 3, lx = lane & 7;
    v2f a0 = {0.f,0.f}, a1 = {0.f,0.f}, a2 = {0.f,0.f}, a3 = {0.f,0.f};

    int nf = d >> 3;
    #pragma unroll 2
    for (int t = 0; t < nf; ++t) {
        int j = beg + t * 8;
        int s0 = csr[j],     s1 = csr[j + 1], s2 = csr[j + 2], s3 = csr[j + 3];
        int s4 = csr[j + 4], s5 = csr[j + 5], s6 = csr[j + 6], s7 = csr[j + 7];
        int t0 = (lane & 8) ? s1 : s0; int t1 = (lane & 8) ? s3 : s2;
        int t2 = (lane & 8) ? s5 : s4; int t3 = (lane & 8) ? s7 : s6;
        int u0 = (lane & 16) ? t1 : t0; int u1 = (lane & 16) ? t3 : t2;
        int ss = (lane & 32) ? u1 : u0;
        uint4 v = ((const uint4*)(p + (size_t)ss * 64))[lx];
        a0 += cvt2(v.x); a1 += cvt2(v.y); a2 += cvt2(v.z); a3 += cvt2(v.w);
    }
    int rem = d & 7;
    if (rem) {
        int j = beg + nf * 8;
        int rc = rem - 1;
        int s0 = csr[j];
        int s1 = csr[j + min(1, rc)]; int s2 = csr[j + min(2, rc)];
        int s3 = csr[j + min(3, rc)]; int s4 = csr[j + min(4, rc)];
        int s5 = csr[j + min(5, rc)]; int s6 = csr[j + min(6, rc)];
        int s7 = csr[j + min(7, rc)];
        int t0 = (lane & 8) ? s1 : s0; int t1 = (lane & 8) ? s3 : s2;
        int t2 = (lane & 8) ? s5 : s4; int t3 = (lane & 8) ? s7 : s6;
        int u0 = (lane & 16) ? t1 : t0; int u1 = (lane & 16) ? t3 : t2;
        int ss = (lane & 32) ? u1 : u0;
        uint4 v = ((const uint4*)(p + (size_t)ss * 64))[lx];
        bool ok = grp < rem;
        v.x = ok ? v.x : 0u; v.y = ok ? v.y : 0u;
        v.z = ok ? v.z : 0u; v.w = ok ? v.w : 0u;
        a0 += cvt2(v.x); a1 += cvt2(v.y); a2 += cvt2(v.z); a3 += cvt2(v.w);
    }
    // reduce the 8 replicas (lane bits 3,4,5)
    #pragma unroll
    for (int m = 8; m <= 32; m <<= 1) {
        a0.x += __shfl_xor(a0.x, m); a0.y += __shfl_xor(a0.y, m);
        a1.x += __shfl_xor(a1.x, m); a1.y += __shfl_xor(a1.y, m);
        a2.x += __shfl_xor(a2.x, m); a2.y += __shfl_xor(a2.y, m);
        a3.x += __shfl_xor(a3.x, m); a3.y += __shfl_xor(a3.y, m);
    }
    if (grp == 0) {
        float ic = invc[wid], dd = dis[wid];
        uint4 qv = ((const uint4*)(q + (size_t)wid * 64))[lx];
        v2f q0 = cvt2(qv.x), q1 = cvt2(qv.y), q2 = cvt2(qv.z), q3 = cvt2(qv.w);
        uint4 o;
        o.x = (unsigned)f2bf(dd * (a0.x * ic + q0.x)) | ((unsigned)f2bf(dd * (a0.y * ic + q0.y)) << 16);
        o.y = (unsigned)f2bf(dd * (a1.x * ic + q1.x)) | ((unsigned)f2bf(dd * (a1.y * ic + q1.y)) << 16);
        o.z = (unsigned)f2bf(dd * (a2.x * ic + q2.x)) | ((unsigned)f2bf(dd * (a2.y * ic + q2.y)) << 16);
        o.w = (unsigned)f2bf(dd * (a3.x * ic + q3.x)) | ((unsigned)f2bf(dd * (a3.y * ic + q3.y)) << 16);
        ((uint4*)(h2s + (size_t)wid * 64))[lx] = o;
    }
}

// iconv v3: out[d] = dis_d * (h2s[d] + sum_in h2s[s]); same 8-rows/instr.
__global__ __launch_bounds__(256) void iconv_kernel(
    float* __restrict__ out, const unsigned short* __restrict__ h2s,
    const float* __restrict__ dis, const int* __restrict__ row_ptr,
    const int* __restrict__ csr, int N)
{
    int wid = (blockIdx.x * 256 + threadIdx.x) >> 6;
    int lane = threadIdx.x & 63;
    if (wid >= N) return;
    int beg = __builtin_amdgcn_readfirstlane(row_ptr[wid]);
    int end = __builtin_amdgcn_readfirstlane(row_ptr[wid + 1]);
    int d = end - beg;
    int grp = lane >> 3, lx = lane & 7;
    v2f a0 = {0.f,0.f}, a1 = {0.f,0.f}, a2 = {0.f,0.f}, a3 = {0.f,0.f};

    int nf = d >> 3;
    #pragma unroll 2
    for (int t = 0; t < nf; ++t) {
        int j = beg + t * 8;
        int s0 = csr[j],     s1 = csr[j + 1], s2 = csr[j + 2], s3 = csr[j + 3];
        int s4 = csr[j + 4], s5 = csr[j + 5], s6 = csr[j + 6], s7 = csr[j + 7];
        int t0 = (lane & 8) ? s1 : s0; int t1 = (lane & 8) ? s3 : s2;
        int t2 = (lane & 8) ? s5 : s4; int t3 = (lane & 8) ? s7 : s6;
        int u0 = (lane & 16) ? t1 : t0; int u1 = (lane & 16) ? t3 : t2;
        int ss = (lane & 32) ? u1 : u0;
        uint4 v = ((const uint4*)(h2s + (size_t)ss * 64))[lx];
        a0 += cvt2(v.x); a1 += cvt2(v.y); a2 += cvt2(v.z); a3 += cvt2(v.w);
    }
    int rem = d & 7;
    if (rem) {
        int j = beg + nf * 8;
        int rc = rem - 1;
        int s0 = csr[j];
        int s1 = csr[j + min(1, rc)]; int s2 = csr[j + min(2, rc)];
        int s3 = csr[j + min(3, rc)]; int s4 = csr[j + min(4, rc)];
        int s5 = csr[j + min(5, rc)]; int s6 = csr[j + min(6, rc)];
        int s7 = csr[j + min(7, rc)];
        int t0 = (lane & 8) ? s1 : s0; int t1 = (lane & 8) ? s3 : s2;
        int t2 = (lane & 8) ? s5 : s4; int t3 = (lane & 8) ? s7 : s6;
        int u0 = (lane & 16) ? t1 : t0; int u1 = (lane & 16) ? t3 : t2;
        int ss = (lane & 32) ? u1 : u0;
        uint4 v = ((const uint4*)(h2s + (size_t)ss * 64))[lx];
        bool ok = grp < rem;
        v.x = ok ? v.x : 0u; v.y = ok ? v.y : 0u;
        v.z = ok ? v.z : 0u; v.w = ok ? v.w : 0u;
        a0 += cvt2(v.x); a1 += cvt2(v.y); a2 += cvt2(v.z); a3 += cvt2(v.w);
    }
    #pragma unroll
    for (int m = 8; m <= 32; m <<= 1) {
        a0.x += __shfl_xor(a0.x, m); a0.y += __shfl_xor(a0.y, m);
        a1.x += __shfl_xor(a1.x, m); a1.y += __shfl_xor(a1.y, m);
        a2.x += __shfl_xor(a2.x, m); a2.y += __shfl_xor(a2.y, m);
        a3.x += __shfl_xor(a3.x, m); a3.y += __shfl_xor(a3.y, m);
    }
    if (grp == 0) {
        uint4 sv = ((const uint4*)(h2s + (size_t)wid * 64))[lx];   // self term
        v2f s0 = cvt2(sv.x), s1 = cvt2(sv.y), s2 = cvt2(sv.z), s3 = cvt2(sv.w);
        float dd = dis[wid];
        float4 o0 = make_float4(dd * (a0.x + s0.x), dd * (a0.y + s0.y),
                                dd * (a1.x + s1.x), dd * (a1.y + s1.y));
        float4 o1 = make_float4(dd * (a2.x + s2.x), dd * (a2.y + s2.y),
                                dd * (a3.x + s3.x), dd * (a3.y + s3.y));
        ((float4*)(out + (size_t)wid * 64))[lx * 2]     = o0;
        ((float4*)(out + (size_t)wid * 64))[lx * 2 + 1] = o1;
    }
}

// ---------------------------------------------------------------------------
extern "C" void kernel_launch(void* const* d_in, const int* in_sizes, int n_in,
                              void* d_out, int out_size, void* d_ws, size_t ws_size,
                              hipStream_t stream) {
    const float* x   = (const float*)d_in[0];
    const int*   ei  = (const int*)d_in[1];
    const float* W1l = (const float*)d_in[2];
    const float* b1  = (const float*)d_in[3];
    const float* W1r = (const float*)d_in[4];
    const float* W2l = (const float*)d_in[5];
    const float* b2  = (const float*)d_in[6];
    const float* W2r = (const float*)d_in[7];
    float* out = (float*)d_out;

    const int* src = ei;
    const int* dst = ei + GE;

    // ---- workspace layout ----
    float* invc = (float*)d_ws;                                   // [N]
    float* dis  = invc + GN;                                      // [N]
    unsigned short* regA = (unsigned short*)(dis + GN);           // [N*128]
    unsigned short* regB = regA + (size_t)GN * 128;               // [N*128]
    unsigned short* xb    = regA;
    unsigned short* aggx  = regB;
    unsigned short* w1lb = regB + (size_t)GN * 128; // [128*128]
    unsigned short* w1rb = w1lb + GH * GF;
    unsigned short* w2lb = w1rb + GH * GF;          // [64*128]
    unsigned short* w2rb = w2lb + GC * GH;
    int* row_ptr      = (int*)(w2rb + GC * GH);     // [N+1]
    int* deg          = row_ptr + GN + 1;           // [N]
    int* cursor       = deg + GN;                   // [N]
    int* bsum         = cursor + GN;                // [NB]
    int* csr          = bsum + NB;                  // [E]
    // p,q in a dedicated region (no aliasing with aggx/xb during fused gemm)
    unsigned short* pq = (unsigned short*)(csr + GE);  // [2*N*64] = 25.6 MB
    unsigned short* pb = pq;
    unsigned short* qb = pq + (size_t)GN * 64;
    unsigned short* h2s = regB;   // aggx dead after fused gemm

    const int T = 256;
    const int g_wave = (GN * 64 + T - 1) / T;
    dim3 g_fused((GN + 63) / 64, 1);       // 1563 single-wave blocks

    // 1) prep: degree atomics + all bf16 casts in one launch
    hipMemsetAsync(deg, 0, GN * sizeof(int), stream);
    prep_kernel<<<EDGE_BLOCKS + CASTX_BLOCKS + 48, T, 0, stream>>>(
        deg, dst, xb, x, w1lb, w1rb, w2lb, w2rb, W1l, W1r, W2l, W2r);

    // 2) row_ptr/cursor/invc/dis via two tiny scans
    scan1_kernel<<<NB, T, 0, stream>>>(bsum, deg);
    scan2_kernel<<<NB, T, 0, stream>>>(row_ptr, cursor, invc, dis, deg, bsum);

    // 3) csr scatter (global-atomic counting sort)
    scatter_kernel<<<EDGE_BLOCKS, T, 0, stream>>>(csr, cursor, src, dst);

    // 4) aggx = mean-gather(xb)
    gather_mean128_kernel<<<g_wave, T, 0, stream>>>(aggx, xb, invc, row_ptr, csr, GN);

    // 5) fused GEMMs: h = relu(aggx@W1l^T + xb@W1r^T + b1) (LDS-only);
    //    p = h@W2l^T ; q = h@W2r^T + b2
    fused_gemm_kernel<<<g_fused, 64, 0, stream>>>(pb, qb, aggx, xb,
                                                  w1lb, w1rb, w2lb, w2rb,
                                                  b1, b2, GN);

    // 6) h2s = dis*(mean-gather(p) + q)
    gather_combine_kernel<<<g_wave, T, 0, stream>>>(h2s, pb, qb, invc, dis,
                                                    row_ptr, csr, GN);

    // 7) iconv: out[d] = dis_d*(h2s[d] + sum h2s[s])
    iconv_kernel<<<g_wave, T, 0, stream>>>(out, h2s, dis, row_ptr, csr, GN);
}

// Round 8
// 334.419 us; speedup vs baseline: 1.5047x; 1.5047x over previous
//
#include <hip/hip_runtime.h>

// Problem constants (match reference setup_inputs)
#define GN 100000
#define GE 1600000
#define GF 128      // F_IN
#define GH 128      // hidden
#define GC 64       // out channels

#define NB 392      // dst buckets of width 256 (392*256 = 100352 >= N)
#define SLABSZ 5376 // mean 4096, sigma ~64 -> +20 sigma headroom
#define P1_EDGES 4096
#define P1_BLOCKS ((GE + P1_EDGES - 1) / P1_EDGES)   // 391
#define CASTX_BLOCKS 12500                            // GN*GF/4 / 256 exactly

typedef __attribute__((ext_vector_type(8))) short v8s;   // 8 bf16 (4 VGPRs)
typedef __attribute__((ext_vector_type(4))) float v4f;   // 4 fp32
typedef __attribute__((ext_vector_type(2))) float v2f;   // 2 fp32 (pk_add_f32)

__device__ __forceinline__ unsigned short f2bf(float f) {
    union { float f; unsigned u; } a; a.f = f;
    unsigned r = a.u + 0x7fff + ((a.u >> 16) & 1);  // RNE
    return (unsigned short)(r >> 16);
}
__device__ __forceinline__ float bf2f(unsigned short b) {
    union { unsigned u; float f; } a; a.u = ((unsigned)b) << 16;
    return a.f;
}
// word of 2 bf16 -> {lo_as_f32, hi_as_f32}
__device__ __forceinline__ v2f cvt2(unsigned w) {
    union { unsigned u; float f; } lo, hi;
    lo.u = w << 16; hi.u = w & 0xffff0000u;
    return (v2f){lo.f, hi.f};
}

// 256-thread exclusive scan: wave shfl_up scan (no barriers) + 4-entry LDS
// combine (2 barriers total, vs 16 for the Hillis-Steele-in-LDS version).
__device__ __forceinline__ int block_excl_scan256(int v, volatile int* ws, int tid) {
    int lane = tid & 63, w = tid >> 6;
    int s = v;
    #pragma unroll
    for (int off = 1; off < 64; off <<= 1) {
        int t = __shfl_up(s, off);
        if (lane >= off) s += t;
    }
    if (lane == 63) ws[w] = s;
    __syncthreads();
    int wbase = 0;
    if (w > 0) wbase += ws[0];
    if (w > 1) wbase += ws[1];
    if (w > 2) wbase += ws[2];
    __syncthreads();
    return wbase + s - v;
}

// ---------------------------------------------------------------------------
// PREP: blocks [0,391) = bucket pass1; rest = bf16 casts (x + weights).
__global__ __launch_bounds__(256) void prep_kernel(
    unsigned* __restrict__ slab, int* __restrict__ bucket_cnt,
    const int* __restrict__ src, const int* __restrict__ dst,
    unsigned short* __restrict__ xb, const float* __restrict__ x,
    unsigned short* w1l, unsigned short* w1r,
    unsigned short* w2l, unsigned short* w2r,
    const float* W1l, const float* W1r,
    const float* W2l, const float* W2r)
{
    __shared__ int hist[512];
    __shared__ int scanex[512];
    __shared__ int cursor[512];
    __shared__ int gbase[512];
    __shared__ int wsS[4];
    __shared__ unsigned stage[P1_EDGES];
    __shared__ unsigned short sbid[P1_EDGES];

    int tid = threadIdx.x;
    int blk = blockIdx.x;

    if (blk >= P1_BLOCKS) {
        int cb = blk - P1_BLOCKS;
        if (cb < CASTX_BLOCKS) {
            int i = cb * 256 + tid;
            float4 v = ((const float4*)x)[i];
            ushort4 u;
            u.x = f2bf(v.x); u.y = f2bf(v.y); u.z = f2bf(v.z); u.w = f2bf(v.w);
            ((ushort4*)xb)[i] = u;
            return;
        }
        int i = (cb - CASTX_BLOCKS) * 256 + tid;
        const float* s; unsigned short* d; int off;
        if      (i <  4096) { s = W1l; d = w1l; off = i; }
        else if (i <  8192) { s = W1r; d = w1r; off = i - 4096; }
        else if (i < 10240) { s = W2l; d = w2l; off = i - 8192; }
        else if (i < 12288) { s = W2r; d = w2r; off = i - 10240; }
        else return;
        float4 v = ((const float4*)s)[off];
        ushort4 u;
        u.x = f2bf(v.x); u.y = f2bf(v.y); u.z = f2bf(v.z); u.w = f2bf(v.w);
        ((ushort4*)d)[off] = u;
        return;
    }

    // ---- pass1 branch ----
    int e0 = blk * P1_EDGES;
    int nE = min(P1_EDGES, GE - e0);

    unsigned pk[16]; int bk[16];
    hist[tid] = 0; hist[tid + 256] = 0;
    __syncthreads();
    #pragma unroll
    for (int j = 0; j < 16; ++j) {
        int i = j * 256 + tid;
        if (i < nE) {
            int e = e0 + i;
            int d = dst[e], s = src[e];
            int b = d >> 8;
            pk[j] = ((unsigned)(d & 255) << 17) | (unsigned)s;
            bk[j] = b;
            atomicAdd(&hist[b], 1);
        } else bk[j] = -1;
    }
    __syncthreads();
    int a0 = hist[2 * tid], a1 = hist[2 * tid + 1];
    int pbase = block_excl_scan256(a0 + a1, wsS, tid);
    scanex[2 * tid] = pbase;          cursor[2 * tid] = pbase;
    scanex[2 * tid + 1] = pbase + a0; cursor[2 * tid + 1] = pbase + a0;
    __syncthreads();
    #pragma unroll
    for (int j = 0; j < 16; ++j) {
        if (bk[j] >= 0) {
            int pos = atomicAdd(&cursor[bk[j]], 1);
            stage[pos] = pk[j];
            sbid[pos] = (unsigned short)bk[j];
        }
    }
    for (int b = tid; b < NB; b += 256) {
        int c = hist[b];
        gbase[b] = c ? atomicAdd(&bucket_cnt[b], c) : 0;
    }
    __syncthreads();
    for (int i = tid; i < nE; i += 256) {
        int b = sbid[i];
        int go = gbase[b] + (i - scanex[b]);
        if (go < SLABSZ)
            slab[(size_t)b * SLABSZ + go] = stage[i];
    }
}

// PASS 2: per bucket (width 256). Inline scan of bucket counts -> base; LDS
// degree histogram -> row_ptr/invc/dis; LDS scatter -> dst-sorted csr.
__global__ __launch_bounds__(256) void bucket_pass2_kernel(
    int* __restrict__ csr, int* __restrict__ row_ptr,
    float* __restrict__ invc, float* __restrict__ dis,
    const unsigned* __restrict__ slab, const int* __restrict__ bucket_cnt)
{
    __shared__ int deg_l[256];
    __shared__ int cur[256];
    __shared__ int wsS[4];
    __shared__ int bstart_s;
    __shared__ unsigned stage[SLABSZ];

    int t = threadIdx.x;
    int b = blockIdx.x;

    int c0 = (2 * t < NB) ? bucket_cnt[2 * t] : 0;
    int c1 = (2 * t + 1 < NB) ? bucket_cnt[2 * t + 1] : 0;
    int pb = block_excl_scan256(c0 + c1, wsS, t);
    if (2 * t == b)     bstart_s = pb;
    if (2 * t + 1 == b) bstart_s = pb + c0;
    if (b == NB - 1 && t == 0) row_ptr[GN] = GE;

    int cnt = min(bucket_cnt[b], SLABSZ);
    const unsigned* sp = slab + (size_t)b * SLABSZ;
    deg_l[t] = 0;
    __syncthreads();
    int base = bstart_s;
    for (int i = t; i < cnt; i += 256)
        atomicAdd(&deg_l[sp[i] >> 17], 1);
    __syncthreads();
    int dg = deg_l[t];
    int ex = block_excl_scan256(dg, wsS, t);
    cur[t] = ex;
    __syncthreads();
    int d = b * 256 + t;
    if (d < GN) {
        row_ptr[d] = base + ex;
        float c = (float)dg;
        invc[d] = 1.0f / fmaxf(c, 1.0f);
        dis[d] = rsqrtf(c + 1.0f);
    }
    for (int i = t; i < cnt; i += 256) {
        unsigned p = sp[i];
        int pos = atomicAdd(&cur[p >> 17], 1);
        stage[pos] = p & 0x1FFFFu;
    }
    __syncthreads();
    for (int i = t; i < cnt; i += 256)
        csr[base + i] = (int)stage[i];
}

// ---------------------------------------------------------------------------
// FUSED GEMM v2: ONE WAVE PER 64-ROW TILE (no barriers, 17.4 KB LDS/block).
__global__ __launch_bounds__(64, 2) void fused_gemm_kernel(
    unsigned short* __restrict__ P, unsigned short* __restrict__ Q,
    const unsigned short* __restrict__ A1, const unsigned short* __restrict__ A2,
    const unsigned short* __restrict__ W1, const unsigned short* __restrict__ W2,
    const unsigned short* __restrict__ Wl, const unsigned short* __restrict__ Wr,
    const float* __restrict__ b1, const float* __restrict__ b2, int M)
{
    __shared__ unsigned short hs[64][136];   // 17.4 KB; row stride 272B -> 2-way alias (free)

    int lane = threadIdx.x;                  // 0..63, one wave
    int lm = lane & 15, quad = lane >> 4;
    int m_base = blockIdx.x * 64;

    // ---- phase 1: layer-1 dual GEMM, full N=128, A loaded once ----
    v4f acc[4][8];
    #pragma unroll
    for (int mt = 0; mt < 4; ++mt)
        #pragma unroll
        for (int nt = 0; nt < 8; ++nt) acc[mt][nt] = (v4f){0.f,0.f,0.f,0.f};

    #pragma unroll
    for (int ks = 0; ks < 4; ++ks) {
        int koff = ks * 32 + quad * 8;
        v8s a1[4], a2[4];
        #pragma unroll
        for (int mt = 0; mt < 4; ++mt) {
            int row = m_base + mt * 16 + lm;
            if (row < M) {
                a1[mt] = *(const v8s*)(A1 + (size_t)row * 128 + koff);
                a2[mt] = *(const v8s*)(A2 + (size_t)row * 128 + koff);
            } else {
                a1[mt] = (v8s){0,0,0,0,0,0,0,0};
                a2[mt] = (v8s){0,0,0,0,0,0,0,0};
            }
        }
        v8s w1[8], w2[8];
        #pragma unroll
        for (int nt = 0; nt < 8; ++nt) {
            int col = nt * 16 + lm;
            w1[nt] = *(const v8s*)(W1 + (size_t)col * 128 + koff);
            w2[nt] = *(const v8s*)(W2 + (size_t)col * 128 + koff);
        }
        #pragma unroll
        for (int mt = 0; mt < 4; ++mt)
            #pragma unroll
            for (int nt = 0; nt < 8; ++nt) {
                acc[mt][nt] = __builtin_amdgcn_mfma_f32_16x16x32_bf16(a1[mt], w1[nt], acc[mt][nt], 0, 0, 0);
                acc[mt][nt] = __builtin_amdgcn_mfma_f32_16x16x32_bf16(a2[mt], w2[nt], acc[mt][nt], 0, 0, 0);
            }
    }

    // epilogue -> LDS (C layout: col = nt*16+lm, row = mt*16 + quad*4 + r)
    #pragma unroll
    for (int mt = 0; mt < 4; ++mt)
        #pragma unroll
        for (int r = 0; r < 4; ++r) {
            int rl = mt * 16 + quad * 4 + r;
            #pragma unroll
            for (int nt = 0; nt < 8; ++nt) {
                int col = nt * 16 + lm;
                float v = acc[mt][nt][r] + b1[col];
                hs[rl][col] = f2bf(fmaxf(v, 0.f));
            }
        }
    // same-wave LDS RAW: compiler inserts lgkmcnt wait; no barrier needed.

    // ---- phase 2: layer-2 dual GEMM, A from LDS ----
    v4f accP[4][4], accQ[4][4];
    #pragma unroll
    for (int mt = 0; mt < 4; ++mt)
        #pragma unroll
        for (int nt = 0; nt < 4; ++nt) {
            accP[mt][nt] = (v4f){0.f,0.f,0.f,0.f};
            accQ[mt][nt] = (v4f){0.f,0.f,0.f,0.f};
        }

    #pragma unroll
    for (int ks = 0; ks < 4; ++ks) {
        int koff = ks * 32 + quad * 8;
        v8s af[4], bl[4], br[4];
        #pragma unroll
        for (int mt = 0; mt < 4; ++mt)
            af[mt] = *(const v8s*)&hs[mt * 16 + lm][koff];
        #pragma unroll
        for (int nt = 0; nt < 4; ++nt) {
            int col = nt * 16 + lm;
            bl[nt] = *(const v8s*)(Wl + (size_t)col * 128 + koff);
            br[nt] = *(const v8s*)(Wr + (size_t)col * 128 + koff);
        }
        #pragma unroll
        for (int mt = 0; mt < 4; ++mt)
            #pragma unroll
            for (int nt = 0; nt < 4; ++nt) {
                accP[mt][nt] = __builtin_amdgcn_mfma_f32_16x16x32_bf16(af[mt], bl[nt], accP[mt][nt], 0, 0, 0);
                accQ[mt][nt] = __builtin_amdgcn_mfma_f32_16x16x32_bf16(af[mt], br[nt], accQ[mt][nt], 0, 0, 0);
            }
    }

    #pragma unroll
    for (int mt = 0; mt < 4; ++mt)
        #pragma unroll
        for (int r = 0; r < 4; ++r) {
            int row = m_base + mt * 16 + quad * 4 + r;
            if (row >= M) continue;
            #pragma unroll
            for (int nt = 0; nt < 4; ++nt) {
                int col = nt * 16 + lm;
                P[(size_t)row * 64 + col] = f2bf(accP[mt][nt][r]);
                Q[(size_t)row * 64 + col] = f2bf(accQ[mt][nt][r] + b2[col]);
            }
        }
}

// ---------------------------------------------------------------------------
// GATHER v3 (mean over 128-col bf16 rows): one wave per dst row; 16 lanes x
// 16B cover a 256B row -> FOUR rows per dwordx4 instruction. Scalar csr idx
// (wave-uniform), cndmask row-select, shfl_xor(16,32) replica reduce.
__global__ __launch_bounds__(256) void gather_mean128_kernel(
    unsigned short* __restrict__ out, const unsigned short* __restrict__ in,
    const float* __restrict__ invc, const int* __restrict__ row_ptr,
    const int* __restrict__ csr, int N)
{
    int wid = (blockIdx.x * 256 + threadIdx.x) >> 6;
    int lane = threadIdx.x & 63;
    if (wid >= N) return;
    int beg = __builtin_amdgcn_readfirstlane(row_ptr[wid]);
    int end = __builtin_amdgcn_readfirstlane(row_ptr[wid + 1]);
    int d = end - beg;
    int grp = lane >> 4, lx = lane & 15;
    v2f a0 = {0.f,0.f}, a1 = {0.f,0.f}, a2 = {0.f,0.f}, a3 = {0.f,0.f};

    int nf = d >> 2;
    #pragma unroll 4
    for (int t = 0; t < nf; ++t) {
        int j = beg + t * 4;
        int s0 = csr[j], s1 = csr[j + 1], s2 = csr[j + 2], s3 = csr[j + 3];
        int sa = (lane & 16) ? s1 : s0;
        int sb = (lane & 16) ? s3 : s2;
        int ss = (lane & 32) ? sb : sa;
        uint4 v = ((const uint4*)(in + (size_t)ss * 128))[lx];
        a0 += cvt2(v.x); a1 += cvt2(v.y); a2 += cvt2(v.z); a3 += cvt2(v.w);
    }
    int rem = d & 3;
    if (rem) {
        int j = beg + nf * 4;
        int c1 = (rem > 1) ? 1 : 0;
        int c2 = (rem > 2) ? 2 : c1;
        int s0 = csr[j], s1 = csr[j + c1], s2 = csr[j + c2], s3 = s2;
        int sa = (lane & 16) ? s1 : s0;
        int sb = (lane & 16) ? s3 : s2;
        int ss = (lane & 32) ? sb : sa;
        uint4 v = ((const uint4*)(in + (size_t)ss * 128))[lx];
        bool ok = grp < rem;
        v.x = ok ? v.x : 0u; v.y = ok ? v.y : 0u;
        v.z = ok ? v.z : 0u; v.w = ok ? v.w : 0u;
        a0 += cvt2(v.x); a1 += cvt2(v.y); a2 += cvt2(v.z); a3 += cvt2(v.w);
    }
    // reduce the 4 replicas (lane bits 4,5)
    a0.x += __shfl_xor(a0.x, 16); a0.y += __shfl_xor(a0.y, 16);
    a1.x += __shfl_xor(a1.x, 16); a1.y += __shfl_xor(a1.y, 16);
    a2.x += __shfl_xor(a2.x, 16); a2.y += __shfl_xor(a2.y, 16);
    a3.x += __shfl_xor(a3.x, 16); a3.y += __shfl_xor(a3.y, 16);
    a0.x += __shfl_xor(a0.x, 32); a0.y += __shfl_xor(a0.y, 32);
    a1.x += __shfl_xor(a1.x, 32); a1.y += __shfl_xor(a1.y, 32);
    a2.x += __shfl_xor(a2.x, 32); a2.y += __shfl_xor(a2.y, 32);
    a3.x += __shfl_xor(a3.x, 32); a3.y += __shfl_xor(a3.y, 32);
    if (grp == 0) {
        float ic = invc[wid];
        uint4 o;
        o.x = (unsigned)f2bf(a0.x * ic) | ((unsigned)f2bf(a0.y * ic) << 16);
        o.y = (unsigned)f2bf(a1.x * ic) | ((unsigned)f2bf(a1.y * ic) << 16);
        o.z = (unsigned)f2bf(a2.x * ic) | ((unsigned)f2bf(a2.y * ic) << 16);
        o.w = (unsigned)f2bf(a3.x * ic) | ((unsigned)f2bf(a3.y * ic) << 16);
        ((uint4*)(out + (size_t)wid * 128))[lx] = o;
    }
}

// GATHER v3 over p (64-col bf16 rows = 128B): 8 lanes x 16B per row ->
// EIGHT rows per dwordx4 instruction. Same scalar-idx + cndmask-select +
// shfl_xor(8,16,32) reduction. Epilogue folds q, invc, dis.
__global__ __launch_bounds__(256) void gather_combine_kernel(
    unsigned short* __restrict__ h2s, const unsigned short* __restrict__ p,
    const unsigned short* __restrict__ q,
    const float* __restrict__ invc, const float* __restrict__ dis,
    const int* __restrict__ row_ptr, const int* __restrict__ csr, int N)
{
    int wid = (blockIdx.x * 256 + threadIdx.x) >> 6;
    int lane = threadIdx.x & 63;
    if (wid >= N) return;
    int beg = __builtin_amdgcn_readfirstlane(row_ptr[wid]);
    int end = __builtin_amdgcn_readfirstlane(row_ptr[wid + 1]);
    int d = end - beg;
    int grp = lane >> 3, lx = lane & 7;
    v2f a0 = {0.f,0.f}, a1 = {0.f,0.f}, a2 = {0.f,0.f}, a3 = {0.f,0.f};

    int nf = d >> 3;
    #pragma unroll 2
    for (int t = 0; t < nf; ++t) {
        int j = beg + t * 8;
        int s0 = csr[j],     s1 = csr[j + 1], s2 = csr[j + 2], s3 = csr[j + 3];
        int s4 = csr[j + 4], s5 = csr[j + 5], s6 = csr[j + 6], s7 = csr[j + 7];
        int t0 = (lane & 8) ? s1 : s0; int t1 = (lane & 8) ? s3 : s2;
        int t2 = (lane & 8) ? s5 : s4; int t3 = (lane & 8) ? s7 : s6;
        int u0 = (lane & 16) ? t1 : t0; int u1 = (lane & 16) ? t3 : t2;
        int ss = (lane & 32) ? u1 : u0;
        uint4 v = ((const uint4*)(p + (size_t)ss * 64))[lx];
        a0 += cvt2(v.x); a1 += cvt2(v.y); a2 += cvt2(v.z); a3 += cvt2(v.w);
    }
    int rem = d & 7;
    if (rem) {
        int j = beg + nf * 8;
        int rc = rem - 1;
        int s0 = csr[j];
        int s1 = csr[j + min(1, rc)]; int s2 = csr[j + min(2, rc)];
        int s3 = csr[j + min(3, rc)]; int s4 = csr[j + min(4, rc)];
        int s5 = csr[j + min(5, rc)]; int s6 = csr[j + min(6, rc)];
        int s7 = csr[j + min(7, rc)];
        int t0 = (lane & 8) ? s1 : s0; int t1 = (lane & 8) ? s3 : s2;
        int t2 = (lane & 8) ? s5 : s4; int t3 = (lane & 8) ? s7 : s6;
        int u0 = (lane & 16) ? t1 : t0; int u1 = (lane & 16) ? t3 : t2;
        int ss = (lane & 32) ? u1 : u0;
        uint4 v = ((const uint4*)(p + (size_t)ss * 64))[lx];
        bool ok = grp < rem;
        v.x = ok ? v.x : 0u; v.y = ok ? v.y : 0u;
        v.z = ok ? v.z : 0u; v.w = ok ? v.w : 0u;
        a0 += cvt2(v.x); a1 += cvt2(v.y); a2 += cvt2(v.z); a3 += cvt2(v.w);
    }
    // reduce the 8 replicas (lane bits 3,4,5)
    #pragma unroll
    for (int m = 8; m <= 32; m <<= 1) {
        a0.x += __shfl_xor(a0.x, m); a0.y += __shfl_xor(a0.y, m);
        a1.x += __shfl_xor(a1.x, m); a1.y += __shfl_xor(a1.y, m);
        a2.x += __shfl_xor(a2.x, m); a2.y += __shfl_xor(a2.y, m);
        a3.x += __shfl_xor(a3.x, m); a3.y += __shfl_xor(a3.y, m);
    }
    if (grp == 0) {
        float ic = invc[wid], dd = dis[wid];
        uint4 qv = ((const uint4*)(q + (size_t)wid * 64))[lx];
        v2f q0 = cvt2(qv.x), q1 = cvt2(qv.y), q2 = cvt2(qv.z), q3 = cvt2(qv.w);
        uint4 o;
        o.x = (unsigned)f2bf(dd * (a0.x * ic + q0.x)) | ((unsigned)f2bf(dd * (a0.y * ic + q0.y)) << 16);
        o.y = (unsigned)f2bf(dd * (a1.x * ic + q1.x)) | ((unsigned)f2bf(dd * (a1.y * ic + q1.y)) << 16);
        o.z = (unsigned)f2bf(dd * (a2.x * ic + q2.x)) | ((unsigned)f2bf(dd * (a2.y * ic + q2.y)) << 16);
        o.w = (unsigned)f2bf(dd * (a3.x * ic + q3.x)) | ((unsigned)f2bf(dd * (a3.y * ic + q3.y)) << 16);
        ((uint4*)(h2s + (size_t)wid * 64))[lx] = o;
    }
}

// iconv v3: out[d] = dis_d * (h2s[d] + sum_in h2s[s]); same 8-rows/instr.
__global__ __launch_bounds__(256) void iconv_kernel(
    float* __restrict__ out, const unsigned short* __restrict__ h2s,
    const float* __restrict__ dis, const int* __restrict__ row_ptr,
    const int* __restrict__ csr, int N)
{
    int wid = (blockIdx.x * 256 + threadIdx.x) >> 6;
    int lane = threadIdx.x & 63;
    if (wid >= N) return;
    int beg = __builtin_amdgcn_readfirstlane(row_ptr[wid]);
    int end = __builtin_amdgcn_readfirstlane(row_ptr[wid + 1]);
    int d = end - beg;
    int grp = lane >> 3, lx = lane & 7;
    v2f a0 = {0.f,0.f}, a1 = {0.f,0.f}, a2 = {0.f,0.f}, a3 = {0.f,0.f};

    int nf = d >> 3;
    #pragma unroll 2
    for (int t = 0; t < nf; ++t) {
        int j = beg + t * 8;
        int s0 = csr[j],     s1 = csr[j + 1], s2 = csr[j + 2], s3 = csr[j + 3];
        int s4 = csr[j + 4], s5 = csr[j + 5], s6 = csr[j + 6], s7 = csr[j + 7];
        int t0 = (lane & 8) ? s1 : s0; int t1 = (lane & 8) ? s3 : s2;
        int t2 = (lane & 8) ? s5 : s4; int t3 = (lane & 8) ? s7 : s6;
        int u0 = (lane & 16) ? t1 : t0; int u1 = (lane & 16) ? t3 : t2;
        int ss = (lane & 32) ? u1 : u0;
        uint4 v = ((const uint4*)(h2s + (size_t)ss * 64))[lx];
        a0 += cvt2(v.x); a1 += cvt2(v.y); a2 += cvt2(v.z); a3 += cvt2(v.w);
    }
    int rem = d & 7;
    if (rem) {
        int j = beg + nf * 8;
        int rc = rem - 1;
        int s0 = csr[j];
        int s1 = csr[j + min(1, rc)]; int s2 = csr[j + min(2, rc)];
        int s3 = csr[j + min(3, rc)]; int s4 = csr[j + min(4, rc)];
        int s5 = csr[j + min(5, rc)]; int s6 = csr[j + min(6, rc)];
        int s7 = csr[j + min(7, rc)];
        int t0 = (lane & 8) ? s1 : s0; int t1 = (lane & 8) ? s3 : s2;
        int t2 = (lane & 8) ? s5 : s4; int t3 = (lane & 8) ? s7 : s6;
        int u0 = (lane & 16) ? t1 : t0; int u1 = (lane & 16) ? t3 : t2;
        int ss = (lane & 32) ? u1 : u0;
        uint4 v = ((const uint4*)(h2s + (size_t)ss * 64))[lx];
        bool ok = grp < rem;
        v.x = ok ? v.x : 0u; v.y = ok ? v.y : 0u;
        v.z = ok ? v.z : 0u; v.w = ok ? v.w : 0u;
        a0 += cvt2(v.x); a1 += cvt2(v.y); a2 += cvt2(v.z); a3 += cvt2(v.w);
    }
    #pragma unroll
    for (int m = 8; m <= 32; m <<= 1) {
        a0.x += __shfl_xor(a0.x, m); a0.y += __shfl_xor(a0.y, m);
        a1.x += __shfl_xor(a1.x, m); a1.y += __shfl_xor(a1.y, m);
        a2.x += __shfl_xor(a2.x, m); a2.y += __shfl_xor(a2.y, m);
        a3.x += __shfl_xor(a3.x, m); a3.y += __shfl_xor(a3.y, m);
    }
    if (grp == 0) {
        uint4 sv = ((const uint4*)(h2s + (size_t)wid * 64))[lx];   // self term
        v2f s0 = cvt2(sv.x), s1 = cvt2(sv.y), s2 = cvt2(sv.z), s3 = cvt2(sv.w);
        float dd = dis[wid];
        float4 o0 = make_float4(dd * (a0.x + s0.x), dd * (a0.y + s0.y),
                                dd * (a1.x + s1.x), dd * (a1.y + s1.y));
        float4 o1 = make_float4(dd * (a2.x + s2.x), dd * (a2.y + s2.y),
                                dd * (a3.x + s3.x), dd * (a3.y + s3.y));
        ((float4*)(out + (size_t)wid * 64))[lx * 2]     = o0;
        ((float4*)(out + (size_t)wid * 64))[lx * 2 + 1] = o1;
    }
}

// ---------------------------------------------------------------------------
extern "C" void kernel_launch(void* const* d_in, const int* in_sizes, int n_in,
                              void* d_out, int out_size, void* d_ws, size_t ws_size,
                              hipStream_t stream) {
    const float* x   = (const float*)d_in[0];
    const int*   ei  = (const int*)d_in[1];
    const float* W1l = (const float*)d_in[2];
    const float* b1  = (const float*)d_in[3];
    const float* W1r = (const float*)d_in[4];
    const float* W2l = (const float*)d_in[5];
    const float* b2  = (const float*)d_in[6];
    const float* W2r = (const float*)d_in[7];
    float* out = (float*)d_out;

    const int* src = ei;
    const int* dst = ei + GE;

    // ---- workspace layout ----
    float* invc = (float*)d_ws;                                   // [N]
    float* dis  = invc + GN;                                      // [N]
    unsigned short* regA = (unsigned short*)(dis + GN);           // [N*128]
    unsigned short* regB = regA + (size_t)GN * 128;               // [N*128]
    unsigned short* xb    = regA;
    unsigned short* aggx  = regB;
    unsigned short* w1lb = regB + (size_t)GN * 128; // [128*128]
    unsigned short* w1rb = w1lb + GH * GF;
    unsigned short* w2lb = w1rb + GH * GF;          // [64*128]
    unsigned short* w2rb = w2lb + GC * GH;
    int* row_ptr      = (int*)(w2rb + GC * GH);     // [N+1]
    int* bucket_cnt   = row_ptr + GN + 1;           // [NB]
    unsigned* slab    = (unsigned*)(bucket_cnt + NB);        // [NB*SLABSZ]
    int* csr          = (int*)(slab + (size_t)NB * SLABSZ);  // [E]
    // p,q in a dedicated region (no aliasing with aggx/xb during fused gemm)
    unsigned short* pq = (unsigned short*)(csr + GE);  // [2*N*64] = 25.6 MB
    unsigned short* pb = pq;
    unsigned short* qb = pq + (size_t)GN * 64;
    unsigned short* h2s = regB;   // aggx dead after fused gemm

    const int T = 256;
    const int g_wave = (GN * 64 + T - 1) / T;
    dim3 g_fused((GN + 63) / 64, 1);       // 1563 single-wave blocks

    // 1) prep: CSR pass1 + all bf16 casts in one launch
    hipMemsetAsync(bucket_cnt, 0, NB * sizeof(int), stream);
    prep_kernel<<<P1_BLOCKS + CASTX_BLOCKS + 48, T, 0, stream>>>(
        slab, bucket_cnt, src, dst,
        xb, x, w1lb, w1rb, w2lb, w2rb, W1l, W1r, W2l, W2r);

    // 2) CSR pass2 (inline bucket scan)
    bucket_pass2_kernel<<<NB, T, 0, stream>>>(csr, row_ptr, invc, dis,
                                              slab, bucket_cnt);

    // 3) aggx = mean-gather(xb)
    gather_mean128_kernel<<<g_wave, T, 0, stream>>>(aggx, xb, invc, row_ptr, csr, GN);

    // 4) fused GEMMs: h = relu(aggx@W1l^T + xb@W1r^T + b1) (LDS-only);
    //    p = h@W2l^T ; q = h@W2r^T + b2
    fused_gemm_kernel<<<g_fused, 64, 0, stream>>>(pb, qb, aggx, xb,
                                                  w1lb, w1rb, w2lb, w2rb,
                                                  b1, b2, GN);

    // 5) h2s = dis*(mean-gather(p) + q)
    gather_combine_kernel<<<g_wave, T, 0, stream>>>(h2s, pb, qb, invc, dis,
                                                    row_ptr, csr, GN);

    // 6) iconv: out[d] = dis_d*(h2s[d] + sum h2s[s])
    iconv_kernel<<<g_wave, T, 0, stream>>>(out, h2s, dis, row_ptr, csr, GN);
}